// Round 1
// baseline (229.146 us; speedup 1.0000x reference)
//
#include <hip/hip_runtime.h>
#include <hip/hip_bf16.h>
#include <stdint.h>

#define D_MODEL 1024
#define NHEAD   16
#define DK      64
#define SEQ     2048
#define BATCH   2

using bf16 = __bf16;
typedef __bf16 bf16x8 __attribute__((ext_vector_type(8)));
typedef float  f32x4  __attribute__((ext_vector_type(4)));

__device__ __forceinline__ unsigned short f2bf(float x) {
  return __builtin_bit_cast(unsigned short, (__bf16)x);
}

__device__ __forceinline__ void gld_lds16(const void* g, void* l) {
  __builtin_amdgcn_global_load_lds(
      (const __attribute__((address_space(1))) void*)g,
      (__attribute__((address_space(3))) void*)l, 16, 0, 0);
}

// ---------------- f32 -> bf16 conversion (7 segments, sizes compile-time) ---
struct ConvArgs {
  const float* src[7];
  bf16* dst[7];
};

__global__ __launch_bounds__(256) void convert_f32_bf16(ConvArgs a) {
  int v = blockIdx.x * 256 + threadIdx.x;   // one float4 per thread, 4194304 total
  int seg, off;
  if (v < 3 * 1048576) { seg = v >> 20; off = v & (1048576 - 1); }
  else { int u = v - 3 * 1048576; seg = 3 + (u >> 18); off = u & (262144 - 1); }
  float4 f = ((const float4*)a.src[seg])[off];
  ushort4 o;
  o.x = f2bf(f.x); o.y = f2bf(f.y); o.z = f2bf(f.z); o.w = f2bf(f.w);
  ((ushort4*)a.dst[seg])[off] = o;
}

// ---------------- bf16 GEMM: C[m][n] = sum_k A[m][k]*B[n][k] (+bias) --------
// 128x128 tile, BK=64, 4 waves (2x2), wave tile 64x64 = 4x4 frags of 16x16.
// K = D_MODEL = 1024 always. LDS XOR-swizzled via pre-swizzled global source.
// mode 0: out bf16 heads [b][h][s][d], bias[n]   (Q/K projection)
// mode 1: out bf16 V^T   [b][h][d][s], bias[m]   (V projection, A=Wv B=X)
// mode 2: out f32  [m][n], bias[n]               (O projection -> d_out)
__global__ __launch_bounds__(256) void gemm_bt(
    const bf16* __restrict__ A, const bf16* __restrict__ B,
    const float* __restrict__ bias, void* __restrict__ Cout, int mode) {
  __shared__ bf16 As[128 * 64];
  __shared__ bf16 Bs[128 * 64];
  const int tid  = threadIdx.x;
  const int lane = tid & 63;
  const int wave = tid >> 6;
  const int wr = wave >> 1, wc = wave & 1;
  const int t = lane >> 4, q = lane & 15;
  const int bx = blockIdx.x, by = blockIdx.y;

  f32x4 acc[4][4];
#pragma unroll
  for (int i = 0; i < 4; ++i)
#pragma unroll
    for (int j = 0; j < 4; ++j) acc[i][j] = (f32x4){0.f, 0.f, 0.f, 0.f};

  const char* Abase = (const char*)(A + (size_t)bx * 128 * D_MODEL);
  const char* Bbase = (const char*)(B + (size_t)by * 128 * D_MODEL);

  for (int kt = 0; kt < D_MODEL / 64; ++kt) {
#pragma unroll
    for (int i = 0; i < 4; ++i) {
      int c = tid + i * 256;           // 1024 chunks of 16B per operand
      int row = c >> 3, cb = c & 7;
      int src = (cb * 16) ^ ((row & 7) << 4);   // pre-swizzled source (T2)
      gld_lds16(Abase + (size_t)row * (D_MODEL * 2) + kt * 128 + src,
                (char*)As + c * 16);
      gld_lds16(Bbase + (size_t)row * (D_MODEL * 2) + kt * 128 + src,
                (char*)Bs + c * 16);
    }
    asm volatile("s_waitcnt vmcnt(0)" ::: "memory");
    __syncthreads();
#pragma unroll
    for (int ks = 0; ks < 2; ++ks) {
      bf16x8 af[4], bfv[4];
#pragma unroll
      for (int f = 0; f < 4; ++f) {
        int ra = wr * 64 + f * 16 + q;
        int rb = wc * 64 + f * 16 + q;
        af[f]  = *(const bf16x8*)((const char*)As + ra * 128 +
                                  ((ks * 64 + t * 16) ^ ((ra & 7) << 4)));
        bfv[f] = *(const bf16x8*)((const char*)Bs + rb * 128 +
                                  ((ks * 64 + t * 16) ^ ((rb & 7) << 4)));
      }
#pragma unroll
      for (int fm = 0; fm < 4; ++fm)
#pragma unroll
        for (int fn = 0; fn < 4; ++fn)
          acc[fm][fn] = __builtin_amdgcn_mfma_f32_16x16x32_bf16(
              af[fm], bfv[fn], acc[fm][fn], 0, 0, 0);
    }
    __syncthreads();
  }

  // epilogue: lane holds C[row = 16*frag + t*4+jj][col = 16*frag + q]
#pragma unroll
  for (int fm = 0; fm < 4; ++fm)
#pragma unroll
    for (int fn = 0; fn < 4; ++fn)
#pragma unroll
      for (int jj = 0; jj < 4; ++jj) {
        int m = bx * 128 + wr * 64 + fm * 16 + t * 4 + jj;
        int n = by * 128 + wc * 64 + fn * 16 + q;
        float v = acc[fm][fn][jj];
        if (mode == 0) {
          v += bias[n];
          int b = m >> 11, s = m & (SEQ - 1), h = n >> 6, d = n & 63;
          ((bf16*)Cout)[(((size_t)(b * NHEAD + h)) * SEQ + s) * DK + d] = (bf16)v;
        } else if (mode == 1) {
          v += bias[m];
          int h = m >> 6, d = m & 63, b = n >> 11, s = n & (SEQ - 1);
          ((bf16*)Cout)[(((size_t)(b * NHEAD + h)) * DK + d) * SEQ + s] = (bf16)v;
        } else {
          v += bias[n];
          ((float*)Cout)[(size_t)m * D_MODEL + n] = v;
        }
      }
}

// ---------------- flash attention -------------------------------------------
// grid (32 q-tiles, 32 bh). 4 waves x 16 q-rows. KV tiles of 64, swizzled LDS.
// Swapped QK^T: lane owns scores for q-row (lane&15), k_local = g*16+t*4+jreg.
__global__ __launch_bounds__(256) void flash_attn(
    const bf16* __restrict__ Qh, const bf16* __restrict__ Kh,
    const bf16* __restrict__ Vt, bf16* __restrict__ ctx) {
  __shared__ bf16 Ks[64 * 64];
  __shared__ bf16 Vs[64 * 64];   // V^T tile: rows = d, cols = k
  const int tid = threadIdx.x;
  const int lane = tid & 63, wave = tid >> 6;
  const int t = lane >> 4, q = lane & 15;
  const int bh = blockIdx.y;
  const int q0 = blockIdx.x * 64 + wave * 16;
  const char* Qb = (const char*)(Qh + (size_t)bh * SEQ * DK);
  const char* Kb = (const char*)(Kh + (size_t)bh * SEQ * DK);
  const char* Vb = (const char*)(Vt + (size_t)bh * DK * SEQ);

  bf16x8 qf[2];   // Q fragment, reused every tile as the MFMA B-operand
  qf[0] = *(const bf16x8*)(Qb + (size_t)(q0 + q) * 128 + t * 16);
  qf[1] = *(const bf16x8*)(Qb + (size_t)(q0 + q) * 128 + 64 + t * 16);

  float mrun = -INFINITY, lrun = 0.f;
  f32x4 acc[4];
#pragma unroll
  for (int dg = 0; dg < 4; ++dg) acc[dg] = (f32x4){0.f, 0.f, 0.f, 0.f};

  const float kSc = 0.18033688011112042f;   // log2(e) / sqrt(64)

  for (int kt = 0; kt < SEQ / 64; ++kt) {
    __syncthreads();
#pragma unroll
    for (int i = 0; i < 2; ++i) {
      int c = tid + i * 256;          // 512 chunks of 16B per buffer
      int row = c >> 3, cb = c & 7;
      int src = (cb * 16) ^ ((row & 7) << 4);
      gld_lds16(Kb + (size_t)(kt * 64 + row) * 128 + src, (char*)Ks + c * 16);
      gld_lds16(Vb + (size_t)row * 4096 + kt * 128 + src, (char*)Vs + c * 16);
    }
    asm volatile("s_waitcnt vmcnt(0)" ::: "memory");
    __syncthreads();

    // S^T = K_tile . Q^T  (4 groups of 16 k-rows)
    f32x4 sg[4];
#pragma unroll
    for (int g = 0; g < 4; ++g) {
      f32x4 s = (f32x4){0.f, 0.f, 0.f, 0.f};
      int row = g * 16 + q;
      int key = (row & 7) << 4;
      bf16x8 kf0 = *(const bf16x8*)((const char*)Ks + row * 128 + ((t * 16) ^ key));
      bf16x8 kf1 = *(const bf16x8*)((const char*)Ks + row * 128 + ((64 + t * 16) ^ key));
      s = __builtin_amdgcn_mfma_f32_16x16x32_bf16(kf0, qf[0], s, 0, 0, 0);
      s = __builtin_amdgcn_mfma_f32_16x16x32_bf16(kf1, qf[1], s, 0, 0, 0);
      sg[g] = s;
    }

    // online softmax (lane owns q-row = lane&15; 16 scores here, 64 via shfl)
    float p[16];
    float mt = -INFINITY;
#pragma unroll
    for (int g = 0; g < 4; ++g)
#pragma unroll
      for (int j = 0; j < 4; ++j) {
        float tv = sg[g][j] * kSc;
        p[g * 4 + j] = tv;
        mt = fmaxf(mt, tv);
      }
    mt = fmaxf(mt, __shfl_xor(mt, 16));
    mt = fmaxf(mt, __shfl_xor(mt, 32));
    float mnew = fmaxf(mrun, mt);
    float corr = exp2f(mrun - mnew);
    float psum = 0.f;
#pragma unroll
    for (int i = 0; i < 16; ++i) { p[i] = exp2f(p[i] - mnew); psum += p[i]; }
    psum += __shfl_xor(psum, 16);
    psum += __shfl_xor(psum, 32);
    lrun = lrun * corr + psum;
    mrun = mnew;

    // rescale O (O-rows are t*4+jj; its corr lives at lane q' = t*4+jj)
    float cb4[4];
#pragma unroll
    for (int j = 0; j < 4; ++j) cb4[j] = __shfl(corr, t * 4 + j);
#pragma unroll
    for (int dg = 0; dg < 4; ++dg)
#pragma unroll
      for (int j = 0; j < 4; ++j) acc[dg][j] *= cb4[j];

    // P: C-layout -> A-layout via 16 shfl (index algebra verified per-lane)
    unsigned pk[4][2];
#pragma unroll
    for (int g = 0; g < 4; ++g) {
      pk[g][0] = (unsigned)f2bf(p[g * 4 + 0]) | ((unsigned)f2bf(p[g * 4 + 1]) << 16);
      pk[g][1] = (unsigned)f2bf(p[g * 4 + 2]) | ((unsigned)f2bf(p[g * 4 + 3]) << 16);
    }
    int srcA = q + ((t & 1) << 5);
    int srcB = srcA + 16;
    bool sel = (t >> 1) & 1;
#pragma unroll
    for (int ks = 0; ks < 2; ++ks) {
      unsigned a0l = __shfl(pk[2 * ks][0], srcA), a0h = __shfl(pk[2 * ks][1], srcA);
      unsigned a1l = __shfl(pk[2 * ks + 1][0], srcA), a1h = __shfl(pk[2 * ks + 1][1], srcA);
      unsigned b0l = __shfl(pk[2 * ks][0], srcB), b0h = __shfl(pk[2 * ks][1], srcB);
      unsigned b1l = __shfl(pk[2 * ks + 1][0], srcB), b1h = __shfl(pk[2 * ks + 1][1], srcB);
      uint4 w;
      w.x = sel ? a1l : a0l;
      w.y = sel ? a1h : a0h;
      w.z = sel ? b1l : b0l;
      w.w = sel ? b1h : b0h;
      bf16x8 pa = __builtin_bit_cast(bf16x8, w);
#pragma unroll
      for (int dg = 0; dg < 4; ++dg) {
        int row = dg * 16 + q;
        int key = (row & 7) << 4;
        bf16x8 vf = *(const bf16x8*)((const char*)Vs + row * 128 +
                                     ((ks * 64 + t * 16) ^ key));
        acc[dg] = __builtin_amdgcn_mfma_f32_16x16x32_bf16(pa, vf, acc[dg], 0, 0, 0);
      }
    }
  }

  // finalize: O rows are t*4+jj, row sums live at lane q' = t*4+jj
  float linv[4];
#pragma unroll
  for (int j = 0; j < 4; ++j) linv[j] = 1.f / __shfl(lrun, t * 4 + j);
  int b = bh >> 4, h = bh & 15;
#pragma unroll
  for (int dg = 0; dg < 4; ++dg)
#pragma unroll
    for (int j = 0; j < 4; ++j) {
      int srow = q0 + t * 4 + j;
      int col = h * 64 + dg * 16 + q;
      ctx[((size_t)(b * SEQ + srow)) * D_MODEL + col] = (bf16)(acc[dg][j] * linv[j]);
    }
}

// ---------------- launch -----------------------------------------------------
extern "C" void kernel_launch(void* const* d_in, const int* in_sizes, int n_in,
                              void* d_out, int out_size, void* d_ws, size_t ws_size,
                              hipStream_t stream) {
  const float* query = (const float*)d_in[0];
  const float* key_  = (const float*)d_in[1];
  const float* value = (const float*)d_in[2];
  const float* w_q = (const float*)d_in[3];
  const float* b_q = (const float*)d_in[4];
  const float* w_k = (const float*)d_in[5];
  const float* b_k = (const float*)d_in[6];
  const float* w_v = (const float*)d_in[7];
  const float* b_v = (const float*)d_in[8];
  const float* w_o = (const float*)d_in[9];
  const float* b_o = (const float*)d_in[10];

  char* ws = (char*)d_ws;
  const size_t MB = 1024 * 1024;
  bf16* bQ  = (bf16*)(ws + 0 * MB);    // 8 MB each for the three activations
  bf16* bK  = (bf16*)(ws + 8 * MB);
  bf16* bV  = (bf16*)(ws + 16 * MB);
  bf16* bWq = (bf16*)(ws + 24 * MB);   // 2 MB each for the four weights
  bf16* bWk = (bf16*)(ws + 26 * MB);
  bf16* bWv = (bf16*)(ws + 28 * MB);
  bf16* bWo = (bf16*)(ws + 30 * MB);
  bf16* Qh  = (bf16*)(ws + 32 * MB);   // [b][h][s][d]
  bf16* Kh  = (bf16*)(ws + 40 * MB);   // [b][h][s][d]
  bf16* Vth = (bf16*)(ws + 48 * MB);   // [b][h][d][s]
  bf16* ctx = (bf16*)(ws + 56 * MB);   // [b*s][d_model]   (total 64 MB)

  ConvArgs ca;
  ca.src[0] = query; ca.src[1] = key_; ca.src[2] = value;
  ca.src[3] = w_q;   ca.src[4] = w_k;  ca.src[5] = w_v; ca.src[6] = w_o;
  ca.dst[0] = bQ;  ca.dst[1] = bK;  ca.dst[2] = bV;
  ca.dst[3] = bWq; ca.dst[4] = bWk; ca.dst[5] = bWv; ca.dst[6] = bWo;
  convert_f32_bf16<<<16384, 256, 0, stream>>>(ca);

  dim3 blk(256);
  gemm_bt<<<dim3(32, 8), blk, 0, stream>>>(bQ, bWq, b_q, Qh, 0);
  gemm_bt<<<dim3(32, 8), blk, 0, stream>>>(bK, bWk, b_k, Kh, 0);
  gemm_bt<<<dim3(8, 32), blk, 0, stream>>>(bWv, bV, b_v, Vth, 1);  // V^T
  flash_attn<<<dim3(32, 32), blk, 0, stream>>>(Qh, Kh, Vth, ctx);
  gemm_bt<<<dim3(32, 8), blk, 0, stream>>>(ctx, bWo, b_o, d_out, 2);
}

// Round 2
// 210.781 us; speedup vs baseline: 1.0871x; 1.0871x over previous
//
#include <hip/hip_runtime.h>
#include <hip/hip_bf16.h>
#include <stdint.h>

#define D_MODEL 1024
#define NHEAD   16
#define DK      64
#define SEQ     2048
#define BATCH   2

using bf16 = __bf16;
typedef __bf16 bf16x8 __attribute__((ext_vector_type(8)));
typedef float  f32x4  __attribute__((ext_vector_type(4)));
typedef float  f32x16 __attribute__((ext_vector_type(16)));
typedef unsigned uintx2 __attribute__((ext_vector_type(2)));

__device__ __forceinline__ unsigned short f2bf(float x) {
  return __builtin_bit_cast(unsigned short, (__bf16)x);
}
__device__ __forceinline__ unsigned pk2bf(float a, float b) {
  return (unsigned)f2bf(a) | ((unsigned)f2bf(b) << 16);
}

__device__ __forceinline__ void gld_lds16(const void* g, void* l) {
  __builtin_amdgcn_global_load_lds(
      (const __attribute__((address_space(1))) void*)g,
      (__attribute__((address_space(3))) void*)l, 16, 0, 0);
}

// ---------------- f32 -> bf16 conversion (7 segments, sizes compile-time) ---
struct ConvArgs {
  const float* src[7];
  bf16* dst[7];
};

__global__ __launch_bounds__(256) void convert_f32_bf16(ConvArgs a) {
  int v = blockIdx.x * 256 + threadIdx.x;   // one float4 per thread, 4194304 total
  int seg, off;
  if (v < 3 * 1048576) { seg = v >> 20; off = v & (1048576 - 1); }
  else { int u = v - 3 * 1048576; seg = 3 + (u >> 18); off = u & (262144 - 1); }
  float4 f = ((const float4*)a.src[seg])[off];
  ushort4 o;
  o.x = f2bf(f.x); o.y = f2bf(f.y); o.z = f2bf(f.z); o.w = f2bf(f.w);
  ((ushort4*)a.dst[seg])[off] = o;
}

// ---------------- bf16 GEMM core: C[m][n] = sum_k A[m][k]*B[n][k] (+bias) ---
// BM x 128 tile, BK=64, 4 waves (2x2). K = D_MODEL = 1024.
// mode 0: out bf16 heads [b][h][s][d], bias[n], *oscale  (Q/K projection)
// mode 1: out bf16 V^T   [b][h][d][s], bias[m]           (V projection)
// mode 2: out f32  [m][n], bias[n]                       (O projection)
template <int BM>
__device__ __forceinline__ void gemm_core(
    const bf16* __restrict__ A, const bf16* __restrict__ B,
    const float* __restrict__ bias, void* __restrict__ Cout,
    int mode, int bx, int by, float oscale, char* lds) {
  bf16* As = (bf16*)lds;                 // BM x 64
  bf16* Bs = (bf16*)(lds + BM * 128);    // 128 x 64
  constexpr int FM = BM / 32;            // row-frags per wave
  const int tid  = threadIdx.x;
  const int lane = tid & 63;
  const int wave = tid >> 6;
  const int wr = wave >> 1, wc = wave & 1;
  const int t = lane >> 4, q = lane & 15;

  f32x4 acc[FM][4];
#pragma unroll
  for (int i = 0; i < FM; ++i)
#pragma unroll
    for (int j = 0; j < 4; ++j) acc[i][j] = (f32x4){0.f, 0.f, 0.f, 0.f};

  const char* Abase = (const char*)(A + (size_t)bx * BM * D_MODEL);
  const char* Bbase = (const char*)(B + (size_t)by * 128 * D_MODEL);

  for (int kt = 0; kt < D_MODEL / 64; ++kt) {
#pragma unroll
    for (int i = 0; i < BM / 32; ++i) {          // A: BM*8 16B-chunks
      int c = tid + i * 256;
      int row = c >> 3, cb = c & 7;
      int src = (cb * 16) ^ ((row & 7) << 4);    // pre-swizzled source (T2)
      gld_lds16(Abase + (size_t)row * (D_MODEL * 2) + kt * 128 + src,
                (char*)As + c * 16);
    }
#pragma unroll
    for (int i = 0; i < 4; ++i) {                // B: 1024 16B-chunks
      int c = tid + i * 256;
      int row = c >> 3, cb = c & 7;
      int src = (cb * 16) ^ ((row & 7) << 4);
      gld_lds16(Bbase + (size_t)row * (D_MODEL * 2) + kt * 128 + src,
                (char*)Bs + c * 16);
    }
    asm volatile("s_waitcnt vmcnt(0)" ::: "memory");
    __syncthreads();
#pragma unroll
    for (int ks = 0; ks < 2; ++ks) {
      bf16x8 af[FM], bfv[4];
#pragma unroll
      for (int f = 0; f < FM; ++f) {
        int ra = wr * (BM / 2) + f * 16 + q;
        af[f] = *(const bf16x8*)((const char*)As + ra * 128 +
                                 ((ks * 64 + t * 16) ^ ((ra & 7) << 4)));
      }
#pragma unroll
      for (int f = 0; f < 4; ++f) {
        int rb = wc * 64 + f * 16 + q;
        bfv[f] = *(const bf16x8*)((const char*)Bs + rb * 128 +
                                  ((ks * 64 + t * 16) ^ ((rb & 7) << 4)));
      }
#pragma unroll
      for (int fm = 0; fm < FM; ++fm)
#pragma unroll
        for (int fn = 0; fn < 4; ++fn)
          acc[fm][fn] = __builtin_amdgcn_mfma_f32_16x16x32_bf16(
              af[fm], bfv[fn], acc[fm][fn], 0, 0, 0);
    }
    __syncthreads();
  }

#pragma unroll
  for (int fm = 0; fm < FM; ++fm)
#pragma unroll
    for (int fn = 0; fn < 4; ++fn)
#pragma unroll
      for (int jj = 0; jj < 4; ++jj) {
        int m = bx * BM + wr * (BM / 2) + fm * 16 + t * 4 + jj;
        int n = by * 128 + wc * 64 + fn * 16 + q;
        float v = acc[fm][fn][jj];
        if (mode == 0) {
          v = (v + bias[n]) * oscale;
          int b = m >> 11, s = m & (SEQ - 1), h = n >> 6, d = n & 63;
          ((bf16*)Cout)[(((size_t)(b * NHEAD + h)) * SEQ + s) * DK + d] = (bf16)v;
        } else if (mode == 1) {
          v += bias[m];
          int h = m >> 6, d = m & 63, b = n >> 11, s = n & (SEQ - 1);
          ((bf16*)Cout)[(((size_t)(b * NHEAD + h)) * DK + d) * SEQ + s] = (bf16)v;
        } else {
          v += bias[n];
          ((float*)Cout)[(size_t)m * D_MODEL + n] = v;
        }
      }
}

struct QkvArgs {
  const bf16* A[3]; const bf16* B[3]; const float* bias[3]; bf16* out[3];
};

// fused Q/K/V projections: grid (32, 8, 3) = 768 blocks = 3 blocks/CU
__global__ __launch_bounds__(256) void gemm_qkv(QkvArgs a) {
  __shared__ char lds[128 * 128 + 128 * 128];   // 32 KB
  int z = blockIdx.z;
  int mode = (z == 2) ? 1 : 0;
  int bx = (z == 2) ? blockIdx.y : blockIdx.x;  // z==2: M=1024 (Wv rows)
  int by = (z == 2) ? blockIdx.x : blockIdx.y;  // z==2: N=4096 (tokens)
  float osc = (z == 0) ? 0.18033688011112042f : 1.0f;  // fold log2(e)/8 into Q
  gemm_core<128>(a.A[z], a.B[z], a.bias[z], a.out[z], mode, bx, by, osc, lds);
}

// O projection: BM=64 -> grid (64, 8) = 512 blocks = 2 blocks/CU
__global__ __launch_bounds__(256) void gemm_o(
    const bf16* __restrict__ A, const bf16* __restrict__ B,
    const float* __restrict__ bias, float* __restrict__ Cout) {
  __shared__ char lds[64 * 128 + 128 * 128];    // 24 KB
  gemm_core<64>(A, B, bias, Cout, 2, blockIdx.x, blockIdx.y, 1.0f, lds);
}

// ---------------- flash attention, 32x32 swapped, no LDS --------------------
// grid (32 bh, 16). 4 independent waves/block, each owns 32 q-rows.
// KV tile 64. K/V fragments read straight from global (L2-resident, 256KB/bh).
// Swapped QK^T: S^T[k][q] = mfma(A=K, B=Q); lane owns q-row (lane&31),
// k-rows (r&3)+8*(r>>2)+4*hi per reg. Scores arrive pre-scaled by log2e/8
// (folded into Q projection).
__global__ __launch_bounds__(256) void flash_attn(
    const bf16* __restrict__ Qh, const bf16* __restrict__ Kh,
    const bf16* __restrict__ Vt, bf16* __restrict__ ctx) {
  const int tid  = threadIdx.x;
  const int lane = tid & 63;
  const int wave = tid >> 6;
  const int lo = lane & 31;
  const int hi = lane >> 5;
  const int bh = blockIdx.x;                 // fast-varying -> per-XCD K/V locality
  const int q0 = blockIdx.y * 128 + wave * 32;

  const bf16* Qb = Qh + (size_t)bh * SEQ * DK;
  const bf16* Kb = Kh + (size_t)bh * SEQ * DK;
  const bf16* Vb = Vt + (size_t)bh * DK * SEQ;

  bf16x8 qf[4];                              // B-frag: Q[q0+lo][c*16 + hi*8 + e]
#pragma unroll
  for (int c = 0; c < 4; ++c)
    qf[c] = *(const bf16x8*)(Qb + (size_t)(q0 + lo) * DK + c * 16 + hi * 8);

  f32x16 acc0 = {}, acc1 = {};               // O[q'][d], d = lo (+0 / +32)
  float mrun = -INFINITY, lrun = 0.f;

  for (int kt = 0; kt < SEQ / 64; ++kt) {
    const bf16* Kt = Kb + (size_t)kt * 64 * DK;
    bf16x8 kf[2][4];                         // A-frag: K[st*32+lo][c*16+hi*8+e]
#pragma unroll
    for (int st = 0; st < 2; ++st)
#pragma unroll
      for (int c = 0; c < 4; ++c)
        kf[st][c] = *(const bf16x8*)(Kt + (size_t)(st * 32 + lo) * DK + c * 16 + hi * 8);
    bf16x8 vf[2][4];                         // B-frag: V^T[dt*32+lo][k...]
#pragma unroll
    for (int dt = 0; dt < 2; ++dt)
#pragma unroll
      for (int ks = 0; ks < 4; ++ks)
        vf[dt][ks] = *(const bf16x8*)(Vb + (size_t)(dt * 32 + lo) * SEQ +
                                      kt * 64 + ks * 16 + hi * 8);

    f32x16 s0 = {}, s1 = {};
#pragma unroll
    for (int c = 0; c < 4; ++c)
      s0 = __builtin_amdgcn_mfma_f32_32x32x16_bf16(kf[0][c], qf[c], s0, 0, 0, 0);
#pragma unroll
    for (int c = 0; c < 4; ++c)
      s1 = __builtin_amdgcn_mfma_f32_32x32x16_bf16(kf[1][c], qf[c], s1, 0, 0, 0);

    // online softmax with defer-max (T13, THR=8 in exp2 domain)
    float pmax = -INFINITY;
#pragma unroll
    for (int r = 0; r < 16; ++r) pmax = fmaxf(pmax, fmaxf(s0[r], s1[r]));
    pmax = fmaxf(pmax, __shfl_xor(pmax, 32));

    if (!__all(pmax - mrun <= 8.f)) {        // wave-uniform, rare after tile 0
      float mnew = fmaxf(mrun, pmax);
      float corr = exp2f(mrun - mnew);
      lrun *= corr;
#pragma unroll
      for (int r = 0; r < 16; ++r) {
        int row = (r & 3) + 8 * (r >> 2) + 4 * hi;
        float cr = __shfl(corr, row);        // corr for O-row q' lives at lane q'
        acc0[r] *= cr;
        acc1[r] *= cr;
      }
      mrun = mnew;
    }

    float p[32];
    float psum = 0.f;
#pragma unroll
    for (int r = 0; r < 16; ++r) {
      p[r]      = exp2f(s0[r] - mrun);
      p[16 + r] = exp2f(s1[r] - mrun);
      psum += p[r] + p[16 + r];
    }
    psum += __shfl_xor(psum, 32);
    lrun += psum;

    // P (C-layout) -> PV A-frags via pack + permlane32_swap (T12)
    bf16x8 pa[4];
#pragma unroll
    for (int g = 0; g < 4; ++g) {            // g = k-16-chunk within KV-64 tile
      unsigned c0 = pk2bf(p[g * 8 + 0], p[g * 8 + 1]);  // lo:(k0,k1) hi:(k4,k5)
      unsigned c1 = pk2bf(p[g * 8 + 2], p[g * 8 + 3]);  // lo:(k2,k3) hi:(k6,k7)
      unsigned c2 = pk2bf(p[g * 8 + 4], p[g * 8 + 5]);  // lo:(k8,k9) hi:(k12,k13)
      unsigned c3 = pk2bf(p[g * 8 + 6], p[g * 8 + 7]);  // lo:(k10,11) hi:(k14,15)
      uintx2 r02 = __builtin_amdgcn_permlane32_swap(c0, c2, false, false);
      uintx2 r13 = __builtin_amdgcn_permlane32_swap(c1, c3, false, false);
      uint4 w;
      w.x = r02[0];   // e=(0,1):  lo k(0,1)   hi k(8,9)
      w.y = r13[0];   // e=(2,3):  lo k(2,3)   hi k(10,11)
      w.z = r02[1];   // e=(4,5):  lo k(4,5)   hi k(12,13)
      w.w = r13[1];   // e=(6,7):  lo k(6,7)   hi k(14,15)
      pa[g] = __builtin_bit_cast(bf16x8, w);
    }
#pragma unroll
    for (int ks = 0; ks < 4; ++ks) {
      acc0 = __builtin_amdgcn_mfma_f32_32x32x16_bf16(pa[ks], vf[0][ks], acc0, 0, 0, 0);
      acc1 = __builtin_amdgcn_mfma_f32_32x32x16_bf16(pa[ks], vf[1][ks], acc1, 0, 0, 0);
    }
  }

  int b = bh >> 4, h = bh & 15;
#pragma unroll
  for (int r = 0; r < 16; ++r) {
    int row = (r & 3) + 8 * (r >> 2) + 4 * hi;
    float linv = 1.f / __shfl(lrun, row);
    int srow = q0 + row;
    size_t base = ((size_t)(b * SEQ + srow)) * D_MODEL + h * 64 + lo;
    ctx[base]      = (bf16)(acc0[r] * linv);
    ctx[base + 32] = (bf16)(acc1[r] * linv);
  }
}

// ---------------- launch -----------------------------------------------------
extern "C" void kernel_launch(void* const* d_in, const int* in_sizes, int n_in,
                              void* d_out, int out_size, void* d_ws, size_t ws_size,
                              hipStream_t stream) {
  const float* query = (const float*)d_in[0];
  const float* key_  = (const float*)d_in[1];
  const float* value = (const float*)d_in[2];
  const float* w_q = (const float*)d_in[3];
  const float* b_q = (const float*)d_in[4];
  const float* w_k = (const float*)d_in[5];
  const float* b_k = (const float*)d_in[6];
  const float* w_v = (const float*)d_in[7];
  const float* b_v = (const float*)d_in[8];
  const float* w_o = (const float*)d_in[9];
  const float* b_o = (const float*)d_in[10];

  char* ws = (char*)d_ws;
  const size_t MB = 1024 * 1024;
  bf16* bQ  = (bf16*)(ws + 0 * MB);
  bf16* bK  = (bf16*)(ws + 8 * MB);
  bf16* bV  = (bf16*)(ws + 16 * MB);
  bf16* bWq = (bf16*)(ws + 24 * MB);
  bf16* bWk = (bf16*)(ws + 26 * MB);
  bf16* bWv = (bf16*)(ws + 28 * MB);
  bf16* bWo = (bf16*)(ws + 30 * MB);
  bf16* Qh  = (bf16*)(ws + 32 * MB);   // [b][h][s][d]  (pre-scaled by log2e/8)
  bf16* Kh  = (bf16*)(ws + 40 * MB);   // [b][h][s][d]
  bf16* Vth = (bf16*)(ws + 48 * MB);   // [b][h][d][s]
  bf16* ctx = (bf16*)(ws + 56 * MB);   // [b*s][d_model]

  ConvArgs ca;
  ca.src[0] = query; ca.src[1] = key_; ca.src[2] = value;
  ca.src[3] = w_q;   ca.src[4] = w_k;  ca.src[5] = w_v; ca.src[6] = w_o;
  ca.dst[0] = bQ;  ca.dst[1] = bK;  ca.dst[2] = bV;
  ca.dst[3] = bWq; ca.dst[4] = bWk; ca.dst[5] = bWv; ca.dst[6] = bWo;
  convert_f32_bf16<<<16384, 256, 0, stream>>>(ca);

  QkvArgs qa;
  qa.A[0] = bQ;  qa.B[0] = bWq; qa.bias[0] = b_q; qa.out[0] = Qh;
  qa.A[1] = bK;  qa.B[1] = bWk; qa.bias[1] = b_k; qa.out[1] = Kh;
  qa.A[2] = bWv; qa.B[2] = bV;  qa.bias[2] = b_v; qa.out[2] = Vth;
  gemm_qkv<<<dim3(32, 8, 3), 256, 0, stream>>>(qa);

  flash_attn<<<dim3(32, 16), 256, 0, stream>>>(Qh, Kh, Vth, ctx);

  gemm_o<<<dim3(64, 8), 256, 0, stream>>>(ctx, bWo, b_o, (float*)d_out);
}

// Round 3
// 172.321 us; speedup vs baseline: 1.3298x; 1.2232x over previous
//
#include <hip/hip_runtime.h>
#include <hip/hip_bf16.h>
#include <stdint.h>

#define D_MODEL 1024
#define NHEAD   16
#define DK      64
#define SEQ     2048
#define BATCH   2

using bf16 = __bf16;
typedef __bf16 bf16x8 __attribute__((ext_vector_type(8)));
typedef float  f32x4  __attribute__((ext_vector_type(4)));
typedef float  f32x16 __attribute__((ext_vector_type(16)));
typedef unsigned uintx2 __attribute__((ext_vector_type(2)));

__device__ __forceinline__ unsigned short f2bf(float x) {
  return __builtin_bit_cast(unsigned short, (__bf16)x);
}
__device__ __forceinline__ unsigned pk2bf(float a, float b) {
  return (unsigned)f2bf(a) | ((unsigned)f2bf(b) << 16);
}

__device__ __forceinline__ void gld_lds16(const void* g, void* l) {
  __builtin_amdgcn_global_load_lds(
      (const __attribute__((address_space(1))) void*)g,
      (__attribute__((address_space(3))) void*)l, 16, 0, 0);
}

// ---------------- f32 -> bf16 conversion (7 segments, sizes compile-time) ---
struct ConvArgs {
  const float* src[7];
  bf16* dst[7];
};

__global__ __launch_bounds__(256) void convert_f32_bf16(ConvArgs a) {
  int v = blockIdx.x * 256 + threadIdx.x;   // one float4 per thread, 4194304 total
  int seg, off;
  if (v < 3 * 1048576) { seg = v >> 20; off = v & (1048576 - 1); }
  else { int u = v - 3 * 1048576; seg = 3 + (u >> 18); off = u & (262144 - 1); }
  float4 f = ((const float4*)a.src[seg])[off];
  ushort4 o;
  o.x = f2bf(f.x); o.y = f2bf(f.y); o.z = f2bf(f.z); o.w = f2bf(f.w);
  ((ushort4*)a.dst[seg])[off] = o;
}

// ---------------- bf16 GEMM core: C[m][n] = sum_k A[m][k]*B[n][k] (+bias) ---
// BM x 128 tile, BK=64, 4 waves (2x2). K = D_MODEL = 1024.
// mode 0: out bf16 heads [b][h][s][d], bias[n], *oscale  (Q/K projection)
// mode 1: out bf16 V^T   [b][h][d][s], bias[m]           (V projection)
// mode 2: out f32  [m][n], bias[n]                       (O projection)
template <int BM>
__device__ __forceinline__ void gemm_core(
    const bf16* __restrict__ A, const bf16* __restrict__ B,
    const float* __restrict__ bias, void* __restrict__ Cout,
    int mode, int bx, int by, float oscale, char* lds) {
  bf16* As = (bf16*)lds;                 // BM x 64
  bf16* Bs = (bf16*)(lds + BM * 128);    // 128 x 64
  constexpr int FM = BM / 32;            // row-frags per wave
  const int tid  = threadIdx.x;
  const int lane = tid & 63;
  const int wave = tid >> 6;
  const int wr = wave >> 1, wc = wave & 1;
  const int t = lane >> 4, q = lane & 15;

  f32x4 acc[FM][4];
#pragma unroll
  for (int i = 0; i < FM; ++i)
#pragma unroll
    for (int j = 0; j < 4; ++j) acc[i][j] = (f32x4){0.f, 0.f, 0.f, 0.f};

  const char* Abase = (const char*)(A + (size_t)bx * BM * D_MODEL);
  const char* Bbase = (const char*)(B + (size_t)by * 128 * D_MODEL);

  for (int kt = 0; kt < D_MODEL / 64; ++kt) {
#pragma unroll
    for (int i = 0; i < BM / 32; ++i) {          // A: BM*8 16B-chunks
      int c = tid + i * 256;
      int row = c >> 3, cb = c & 7;
      int src = (cb * 16) ^ ((row & 7) << 4);    // pre-swizzled source (T2)
      gld_lds16(Abase + (size_t)row * (D_MODEL * 2) + kt * 128 + src,
                (char*)As + c * 16);
    }
#pragma unroll
    for (int i = 0; i < 4; ++i) {                // B: 1024 16B-chunks
      int c = tid + i * 256;
      int row = c >> 3, cb = c & 7;
      int src = (cb * 16) ^ ((row & 7) << 4);
      gld_lds16(Bbase + (size_t)row * (D_MODEL * 2) + kt * 128 + src,
                (char*)Bs + c * 16);
    }
    asm volatile("s_waitcnt vmcnt(0)" ::: "memory");
    __syncthreads();
#pragma unroll
    for (int ks = 0; ks < 2; ++ks) {
      bf16x8 af[FM], bfv[4];
#pragma unroll
      for (int f = 0; f < FM; ++f) {
        int ra = wr * (BM / 2) + f * 16 + q;
        af[f] = *(const bf16x8*)((const char*)As + ra * 128 +
                                 ((ks * 64 + t * 16) ^ ((ra & 7) << 4)));
      }
#pragma unroll
      for (int f = 0; f < 4; ++f) {
        int rb = wc * 64 + f * 16 + q;
        bfv[f] = *(const bf16x8*)((const char*)Bs + rb * 128 +
                                  ((ks * 64 + t * 16) ^ ((rb & 7) << 4)));
      }
#pragma unroll
      for (int fm = 0; fm < FM; ++fm)
#pragma unroll
        for (int fn = 0; fn < 4; ++fn)
          acc[fm][fn] = __builtin_amdgcn_mfma_f32_16x16x32_bf16(
              af[fm], bfv[fn], acc[fm][fn], 0, 0, 0);
    }
    __syncthreads();
  }

#pragma unroll
  for (int fm = 0; fm < FM; ++fm)
#pragma unroll
    for (int fn = 0; fn < 4; ++fn)
#pragma unroll
      for (int jj = 0; jj < 4; ++jj) {
        int m = bx * BM + wr * (BM / 2) + fm * 16 + t * 4 + jj;
        int n = by * 128 + wc * 64 + fn * 16 + q;
        float v = acc[fm][fn][jj];
        if (mode == 0) {
          v = (v + bias[n]) * oscale;
          int b = m >> 11, s = m & (SEQ - 1), h = n >> 6, d = n & 63;
          ((bf16*)Cout)[(((size_t)(b * NHEAD + h)) * SEQ + s) * DK + d] = (bf16)v;
        } else if (mode == 1) {
          v += bias[m];
          int h = m >> 6, d = m & 63, b = n >> 11, s = n & (SEQ - 1);
          ((bf16*)Cout)[(((size_t)(b * NHEAD + h)) * DK + d) * SEQ + s] = (bf16)v;
        } else {
          v += bias[n];
          ((float*)Cout)[(size_t)m * D_MODEL + n] = v;
        }
      }
}

struct QkvArgs {
  const bf16* A[3]; const bf16* B[3]; const float* bias[3]; bf16* out[3];
};

// fused Q/K/V projections: grid (32, 8, 3) = 768 blocks = 3 blocks/CU
__global__ __launch_bounds__(256) void gemm_qkv(QkvArgs a) {
  __shared__ char lds[128 * 128 + 128 * 128];   // 32 KB
  int z = blockIdx.z;
  int mode = (z == 2) ? 1 : 0;
  int bx = (z == 2) ? blockIdx.y : blockIdx.x;  // z==2: M=1024 (Wv rows)
  int by = (z == 2) ? blockIdx.x : blockIdx.y;  // z==2: N=4096 (tokens)
  float osc = (z == 0) ? 0.18033688011112042f : 1.0f;  // fold log2(e)/8 into Q
  gemm_core<128>(a.A[z], a.B[z], a.bias[z], a.out[z], mode, bx, by, osc, lds);
}

// O projection: BM=64 -> grid (64, 8) = 512 blocks = 2 blocks/CU
__global__ __launch_bounds__(256) void gemm_o(
    const bf16* __restrict__ A, const bf16* __restrict__ B,
    const float* __restrict__ bias, float* __restrict__ Cout) {
  __shared__ char lds[64 * 128 + 128 * 128];    // 24 KB
  gemm_core<64>(A, B, bias, Cout, 2, blockIdx.x, blockIdx.y, 1.0f, lds);
}

// ---------------- flash attention --------------------------------------------
// 32x32 swapped structure + LDS-staged K/V (double-buffered, XOR-swizzled via
// pre-swizzled global source), 2-phase async pipeline (T3 minimum), setprio (T5).
// grid (32 bh, 16 q-chunks); 4 waves/block, each owns 32 q-rows; KV tile 64.
// Swapped QK^T: S^T[k][q] = mfma(A=K, B=Q); lane owns q-row (lane&31),
// k-rows (r&3)+8*(r>>2)+4*hi per reg. Scores pre-scaled by log2e/8 (in Q proj).
__global__ __launch_bounds__(256) void flash_attn(
    const bf16* __restrict__ Qh, const bf16* __restrict__ Kh,
    const bf16* __restrict__ Vt, bf16* __restrict__ ctx) {
  __shared__ char lds[32768];            // Ks[2] @0,8192 ; Vs[2] @16384,24576
  const int tid  = threadIdx.x;
  const int lane = tid & 63;
  const int wave = tid >> 6;
  const int lo = lane & 31;
  const int hi = lane >> 5;
  const int bh = blockIdx.x;             // fast-varying -> per-XCD K/V locality
  const int q0 = blockIdx.y * 128 + wave * 32;

  const bf16* Qb = Qh + (size_t)bh * SEQ * DK;
  const char* Kb = (const char*)(Kh + (size_t)bh * SEQ * DK);
  const char* Vb = (const char*)(Vt + (size_t)bh * DK * SEQ);

  bf16x8 qf[4];                          // B-frag: Q[q0+lo][c*16 + hi*8 + e]
#pragma unroll
  for (int c = 0; c < 4; ++c)
    qf[c] = *(const bf16x8*)(Qb + (size_t)(q0 + lo) * DK + c * 16 + hi * 8);

  // staging: 512 chunks/operand; thread stages chunks {tid, tid+256} of each.
  const int srow = tid >> 3;                              // 0..31 (and +32)
  const int ssrc = ((tid & 7) * 16) ^ ((srow & 7) << 4);  // pre-swizzled source

  f32x16 acc0 = {}, acc1 = {};           // O[q'][d], d = lo (+0 / +32)
  float mrun = -INFINITY, lrun = 0.f;
  int cur = 0;

  // prologue: stage tile 0 into buffer 0
  gld_lds16(Kb + (size_t)srow * 128 + ssrc,          lds + tid * 16);
  gld_lds16(Kb + (size_t)(srow + 32) * 128 + ssrc,   lds + 4096 + tid * 16);
  gld_lds16(Vb + (size_t)srow * 4096 + ssrc,         lds + 16384 + tid * 16);
  gld_lds16(Vb + (size_t)(srow + 32) * 4096 + ssrc,  lds + 20480 + tid * 16);
  __syncthreads();

  for (int kt = 0; kt < SEQ / 64; ++kt) {
    const char* Kc = lds + cur * 8192;
    const char* Vc = lds + 16384 + cur * 8192;

    // async-stage next tile into the other buffer (lands before end barrier)
    if (kt + 1 < SEQ / 64) {
      const char* Ksrc = Kb + (size_t)(kt + 1) * 64 * 128;
      const char* Vsrc = Vb + (size_t)(kt + 1) * 128;
      char* Kn = lds + (cur ^ 1) * 8192;
      char* Vn = lds + 16384 + (cur ^ 1) * 8192;
      gld_lds16(Ksrc + (size_t)srow * 128 + ssrc,         Kn + tid * 16);
      gld_lds16(Ksrc + (size_t)(srow + 32) * 128 + ssrc,  Kn + 4096 + tid * 16);
      gld_lds16(Vsrc + (size_t)srow * 4096 + ssrc,        Vn + tid * 16);
      gld_lds16(Vsrc + (size_t)(srow + 32) * 4096 + ssrc, Vn + 4096 + tid * 16);
    }

    // K fragments from swizzled LDS: K[st*32+lo][16*(2c+hi) bytes ...]
    bf16x8 kf[2][4];
#pragma unroll
    for (int st = 0; st < 2; ++st)
#pragma unroll
      for (int c = 0; c < 4; ++c) {
        int row = st * 32 + lo;
        kf[st][c] = *(const bf16x8*)(Kc + row * 128 +
                                     (((2 * c + hi) * 16) ^ ((row & 7) << 4)));
      }

    f32x16 s0 = {}, s1 = {};
    __builtin_amdgcn_s_setprio(1);
#pragma unroll
    for (int c = 0; c < 4; ++c)
      s0 = __builtin_amdgcn_mfma_f32_32x32x16_bf16(kf[0][c], qf[c], s0, 0, 0, 0);
#pragma unroll
    for (int c = 0; c < 4; ++c)
      s1 = __builtin_amdgcn_mfma_f32_32x32x16_bf16(kf[1][c], qf[c], s1, 0, 0, 0);
    __builtin_amdgcn_s_setprio(0);

    // online softmax with defer-max (T13, THR=8 in exp2 domain)
    float pmax = -INFINITY;
#pragma unroll
    for (int r = 0; r < 16; ++r) pmax = fmaxf(pmax, fmaxf(s0[r], s1[r]));
    pmax = fmaxf(pmax, __shfl_xor(pmax, 32));

    if (!__all(pmax - mrun <= 8.f)) {    // wave-uniform, rare after tile 0
      float mnew = fmaxf(mrun, pmax);
      float corr = exp2f(mrun - mnew);
      lrun *= corr;
#pragma unroll
      for (int r = 0; r < 16; ++r) {
        int row = (r & 3) + 8 * (r >> 2) + 4 * hi;
        float cr = __shfl(corr, row);    // corr for O-row q' lives at lane q'
        acc0[r] *= cr;
        acc1[r] *= cr;
      }
      mrun = mnew;
    }

    float p[32];
    float psum = 0.f;
#pragma unroll
    for (int r = 0; r < 16; ++r) {
      p[r]      = exp2f(s0[r] - mrun);
      p[16 + r] = exp2f(s1[r] - mrun);
      psum += p[r] + p[16 + r];
    }
    psum += __shfl_xor(psum, 32);
    lrun += psum;

    // P (C-layout) -> PV A-frags via pack + permlane32_swap (T12)
    bf16x8 pa[4];
#pragma unroll
    for (int g = 0; g < 4; ++g) {        // g = k-16-chunk within KV-64 tile
      unsigned c0 = pk2bf(p[g * 8 + 0], p[g * 8 + 1]);
      unsigned c1 = pk2bf(p[g * 8 + 2], p[g * 8 + 3]);
      unsigned c2 = pk2bf(p[g * 8 + 4], p[g * 8 + 5]);
      unsigned c3 = pk2bf(p[g * 8 + 6], p[g * 8 + 7]);
      uintx2 r02 = __builtin_amdgcn_permlane32_swap(c0, c2, false, false);
      uintx2 r13 = __builtin_amdgcn_permlane32_swap(c1, c3, false, false);
      uint4 w;
      w.x = r02[0];
      w.y = r13[0];
      w.z = r02[1];
      w.w = r13[1];
      pa[g] = __builtin_bit_cast(bf16x8, w);
    }

    // V^T fragments from swizzled LDS
    bf16x8 vf[2][4];
#pragma unroll
    for (int dt = 0; dt < 2; ++dt)
#pragma unroll
      for (int ks = 0; ks < 4; ++ks) {
        int row = dt * 32 + lo;
        vf[dt][ks] = *(const bf16x8*)(Vc + row * 128 +
                                      (((2 * ks + hi) * 16) ^ ((row & 7) << 4)));
      }

    __builtin_amdgcn_s_setprio(1);
#pragma unroll
    for (int ks = 0; ks < 4; ++ks) {
      acc0 = __builtin_amdgcn_mfma_f32_32x32x16_bf16(pa[ks], vf[0][ks], acc0, 0, 0, 0);
      acc1 = __builtin_amdgcn_mfma_f32_32x32x16_bf16(pa[ks], vf[1][ks], acc1, 0, 0, 0);
    }
    __builtin_amdgcn_s_setprio(0);

    __syncthreads();                     // drains stage loads; fences dbuf swap
    cur ^= 1;
  }

  int b = bh >> 4, h = bh & 15;
#pragma unroll
  for (int r = 0; r < 16; ++r) {
    int row = (r & 3) + 8 * (r >> 2) + 4 * hi;
    float linv = 1.f / __shfl(lrun, row);
    int srow_ = q0 + row;
    size_t base = ((size_t)(b * SEQ + srow_)) * D_MODEL + h * 64 + lo;
    ctx[base]      = (bf16)(acc0[r] * linv);
    ctx[base + 32] = (bf16)(acc1[r] * linv);
  }
}

// ---------------- launch -----------------------------------------------------
extern "C" void kernel_launch(void* const* d_in, const int* in_sizes, int n_in,
                              void* d_out, int out_size, void* d_ws, size_t ws_size,
                              hipStream_t stream) {
  const float* query = (const float*)d_in[0];
  const float* key_  = (const float*)d_in[1];
  const float* value = (const float*)d_in[2];
  const float* w_q = (const float*)d_in[3];
  const float* b_q = (const float*)d_in[4];
  const float* w_k = (const float*)d_in[5];
  const float* b_k = (const float*)d_in[6];
  const float* w_v = (const float*)d_in[7];
  const float* b_v = (const float*)d_in[8];
  const float* w_o = (const float*)d_in[9];
  const float* b_o = (const float*)d_in[10];

  char* ws = (char*)d_ws;
  const size_t MB = 1024 * 1024;
  bf16* bQ  = (bf16*)(ws + 0 * MB);
  bf16* bK  = (bf16*)(ws + 8 * MB);
  bf16* bV  = (bf16*)(ws + 16 * MB);
  bf16* bWq = (bf16*)(ws + 24 * MB);
  bf16* bWk = (bf16*)(ws + 26 * MB);
  bf16* bWv = (bf16*)(ws + 28 * MB);
  bf16* bWo = (bf16*)(ws + 30 * MB);
  bf16* Qh  = (bf16*)(ws + 32 * MB);   // [b][h][s][d]  (pre-scaled by log2e/8)
  bf16* Kh  = (bf16*)(ws + 40 * MB);   // [b][h][s][d]
  bf16* Vth = (bf16*)(ws + 48 * MB);   // [b][h][d][s]
  bf16* ctx = (bf16*)(ws + 56 * MB);   // [b*s][d_model]

  ConvArgs ca;
  ca.src[0] = query; ca.src[1] = key_; ca.src[2] = value;
  ca.src[3] = w_q;   ca.src[4] = w_k;  ca.src[5] = w_v; ca.src[6] = w_o;
  ca.dst[0] = bQ;  ca.dst[1] = bK;  ca.dst[2] = bV;
  ca.dst[3] = bWq; ca.dst[4] = bWk; ca.dst[5] = bWv; ca.dst[6] = bWo;
  convert_f32_bf16<<<16384, 256, 0, stream>>>(ca);

  QkvArgs qa;
  qa.A[0] = bQ;  qa.B[0] = bWq; qa.bias[0] = b_q; qa.out[0] = Qh;
  qa.A[1] = bK;  qa.B[1] = bWk; qa.bias[1] = b_k; qa.out[1] = Kh;
  qa.A[2] = bWv; qa.B[2] = bV;  qa.bias[2] = b_v; qa.out[2] = Vth;
  gemm_qkv<<<dim3(32, 8, 3), 256, 0, stream>>>(qa);

  flash_attn<<<dim3(32, 16), 256, 0, stream>>>(Qh, Kh, Vth, ctx);

  gemm_o<<<dim3(64, 8), 256, 0, stream>>>(ctx, bWo, b_o, (float*)d_out);
}

// Round 4
// 161.115 us; speedup vs baseline: 1.4223x; 1.0696x over previous
//
#include <hip/hip_runtime.h>
#include <hip/hip_bf16.h>
#include <stdint.h>

#define D_MODEL 1024
#define NHEAD   16
#define DK      64
#define SEQ     2048
#define BATCH   2

using bf16 = __bf16;
typedef __bf16 bf16x8 __attribute__((ext_vector_type(8)));
typedef float  f32x4  __attribute__((ext_vector_type(4)));
typedef float  f32x16 __attribute__((ext_vector_type(16)));
typedef unsigned uintx2 __attribute__((ext_vector_type(2)));

__device__ __forceinline__ unsigned short f2bf(float x) {
  return __builtin_bit_cast(unsigned short, (__bf16)x);
}
__device__ __forceinline__ unsigned pk2bf(float a, float b) {
  return (unsigned)f2bf(a) | ((unsigned)f2bf(b) << 16);
}
__device__ __forceinline__ float uasf(unsigned x) {
  return __builtin_bit_cast(float, x);
}
__device__ __forceinline__ unsigned fasu(float x) {
  return __builtin_bit_cast(unsigned, x);
}

__device__ __forceinline__ void gld_lds16(const void* g, void* l) {
  __builtin_amdgcn_global_load_lds(
      (const __attribute__((address_space(1))) void*)g,
      (__attribute__((address_space(3))) void*)l, 16, 0, 0);
}

// cross-half (lane ^ 32) wave reduction via permlane32_swap (VALU, no LDS)
__device__ __forceinline__ float xhalf_max(float x) {
  uintx2 r = __builtin_amdgcn_permlane32_swap(fasu(x), fasu(x), false, false);
  return fmaxf(uasf(r[0]), uasf(r[1]));
}
__device__ __forceinline__ float xhalf_sum(float x) {
  uintx2 r = __builtin_amdgcn_permlane32_swap(fasu(x), fasu(x), false, false);
  return uasf(r[0]) + uasf(r[1]);
}

// ---------------- f32 -> bf16 conversion (7 segments, sizes compile-time) ---
struct ConvArgs {
  const float* src[7];
  bf16* dst[7];
};

__global__ __launch_bounds__(256) void convert_f32_bf16(ConvArgs a) {
  int v = blockIdx.x * 256 + threadIdx.x;   // one float4 per thread, 4194304 total
  int seg, off;
  if (v < 3 * 1048576) { seg = v >> 20; off = v & (1048576 - 1); }
  else { int u = v - 3 * 1048576; seg = 3 + (u >> 18); off = u & (262144 - 1); }
  float4 f = ((const float4*)a.src[seg])[off];
  ushort4 o;
  o.x = f2bf(f.x); o.y = f2bf(f.y); o.z = f2bf(f.z); o.w = f2bf(f.w);
  ((ushort4*)a.dst[seg])[off] = o;
}

// ---------------- bf16 GEMM core: C[m][n] = sum_k A[m][k]*B[n][k] (+bias) ---
template <int BM>
__device__ __forceinline__ void gemm_core(
    const bf16* __restrict__ A, const bf16* __restrict__ B,
    const float* __restrict__ bias, void* __restrict__ Cout,
    int mode, int bx, int by, float oscale, char* lds) {
  bf16* As = (bf16*)lds;                 // BM x 64
  bf16* Bs = (bf16*)(lds + BM * 128);    // 128 x 64
  constexpr int FM = BM / 32;            // row-frags per wave
  const int tid  = threadIdx.x;
  const int lane = tid & 63;
  const int wave = tid >> 6;
  const int wr = wave >> 1, wc = wave & 1;
  const int t = lane >> 4, q = lane & 15;

  f32x4 acc[FM][4];
#pragma unroll
  for (int i = 0; i < FM; ++i)
#pragma unroll
    for (int j = 0; j < 4; ++j) acc[i][j] = (f32x4){0.f, 0.f, 0.f, 0.f};

  const char* Abase = (const char*)(A + (size_t)bx * BM * D_MODEL);
  const char* Bbase = (const char*)(B + (size_t)by * 128 * D_MODEL);

  for (int kt = 0; kt < D_MODEL / 64; ++kt) {
#pragma unroll
    for (int i = 0; i < BM / 32; ++i) {          // A: BM*8 16B-chunks
      int c = tid + i * 256;
      int row = c >> 3, cb = c & 7;
      int src = (cb * 16) ^ ((row & 7) << 4);    // pre-swizzled source (T2)
      gld_lds16(Abase + (size_t)row * (D_MODEL * 2) + kt * 128 + src,
                (char*)As + c * 16);
    }
#pragma unroll
    for (int i = 0; i < 4; ++i) {                // B: 1024 16B-chunks
      int c = tid + i * 256;
      int row = c >> 3, cb = c & 7;
      int src = (cb * 16) ^ ((row & 7) << 4);
      gld_lds16(Bbase + (size_t)row * (D_MODEL * 2) + kt * 128 + src,
                (char*)Bs + c * 16);
    }
    asm volatile("s_waitcnt vmcnt(0)" ::: "memory");
    __syncthreads();
#pragma unroll
    for (int ks = 0; ks < 2; ++ks) {
      bf16x8 af[FM], bfv[4];
#pragma unroll
      for (int f = 0; f < FM; ++f) {
        int ra = wr * (BM / 2) + f * 16 + q;
        af[f] = *(const bf16x8*)((const char*)As + ra * 128 +
                                 ((ks * 64 + t * 16) ^ ((ra & 7) << 4)));
      }
#pragma unroll
      for (int f = 0; f < 4; ++f) {
        int rb = wc * 64 + f * 16 + q;
        bfv[f] = *(const bf16x8*)((const char*)Bs + rb * 128 +
                                  ((ks * 64 + t * 16) ^ ((rb & 7) << 4)));
      }
#pragma unroll
      for (int fm = 0; fm < FM; ++fm)
#pragma unroll
        for (int fn = 0; fn < 4; ++fn)
          acc[fm][fn] = __builtin_amdgcn_mfma_f32_16x16x32_bf16(
              af[fm], bfv[fn], acc[fm][fn], 0, 0, 0);
    }
    __syncthreads();
  }

#pragma unroll
  for (int fm = 0; fm < FM; ++fm)
#pragma unroll
    for (int fn = 0; fn < 4; ++fn)
#pragma unroll
      for (int jj = 0; jj < 4; ++jj) {
        int m = bx * BM + wr * (BM / 2) + fm * 16 + t * 4 + jj;
        int n = by * 128 + wc * 64 + fn * 16 + q;
        float v = acc[fm][fn][jj];
        if (mode == 0) {
          v = (v + bias[n]) * oscale;
          int b = m >> 11, s = m & (SEQ - 1), h = n >> 6, d = n & 63;
          ((bf16*)Cout)[(((size_t)(b * NHEAD + h)) * SEQ + s) * DK + d] = (bf16)v;
        } else if (mode == 1) {
          v += bias[m];
          int h = m >> 6, d = m & 63, b = n >> 11, s = n & (SEQ - 1);
          ((bf16*)Cout)[(((size_t)(b * NHEAD + h)) * DK + d) * SEQ + s] = (bf16)v;
        } else {
          v += bias[n];
          ((float*)Cout)[(size_t)m * D_MODEL + n] = v;
        }
      }
}

struct QkvArgs {
  const bf16* A[3]; const bf16* B[3]; const float* bias[3]; bf16* out[3];
};

// fused Q/K/V projections: grid (32, 8, 3) = 768 blocks = 3 blocks/CU
__global__ __launch_bounds__(256) void gemm_qkv(QkvArgs a) {
  __shared__ char lds[128 * 128 + 128 * 128];   // 32 KB
  int z = blockIdx.z;
  int mode = (z == 2) ? 1 : 0;
  int bx = (z == 2) ? blockIdx.y : blockIdx.x;  // z==2: M=1024 (Wv rows)
  int by = (z == 2) ? blockIdx.x : blockIdx.y;  // z==2: N=4096 (tokens)
  float osc = (z == 0) ? 0.18033688011112042f : 1.0f;  // fold log2(e)/8 into Q
  gemm_core<128>(a.A[z], a.B[z], a.bias[z], a.out[z], mode, bx, by, osc, lds);
}

// O projection: BM=64 -> grid (64, 8) = 512 blocks = 2 blocks/CU
__global__ __launch_bounds__(256) void gemm_o(
    const bf16* __restrict__ A, const bf16* __restrict__ B,
    const float* __restrict__ bias, float* __restrict__ Cout) {
  __shared__ char lds[64 * 128 + 128 * 128];    // 24 KB
  gemm_core<64>(A, B, bias, Cout, 2, blockIdx.x, blockIdx.y, 1.0f, lds);
}

// ---------------- flash attention --------------------------------------------
// 8 waves = 2 KV-groups x 4 q-waves. Group g processes KV[g*1024,(g+1)*1024)
// for the block's 128 q-rows; partial (m,l,U) merged through LDS at the end.
// Per group: KV tile 64, double-buffered swizzled LDS, 2-phase async pipeline.
// Swapped QK^T (A=K, B=Q): lane owns q-col (lane&31), k-rows crow(r,hi).
// Scores pre-scaled by log2(e)/8 (folded into Q projection).
__global__ __launch_bounds__(512, 4) void flash_attn(
    const bf16* __restrict__ Qh, const bf16* __restrict__ Kh,
    const bf16* __restrict__ Vt, bf16* __restrict__ ctx) {
  __shared__ char lds[65536];   // grp K dbuf @ grp*16384; grp V dbuf @ 32768+grp*16384
  const int tid  = threadIdx.x;
  const int lane = tid & 63;
  const int wave = tid >> 6;
  const int lo = lane & 31;
  const int hi = lane >> 5;
  const int grp = wave >> 2;             // KV half
  const int wq  = wave & 3;              // q sub-block
  const int bh = blockIdx.x;
  const int q0 = blockIdx.y * 128 + wq * 32;

  const bf16* Qb = Qh + (size_t)bh * SEQ * DK;
  const char* Kb = (const char*)(Kh + (size_t)bh * SEQ * DK) + grp * 1024 * 128;
  const char* Vb = (const char*)(Vt + (size_t)bh * DK * SEQ) + grp * 1024 * 2;
  char* Kg = lds + grp * 16384;
  char* Vg = lds + 32768 + grp * 16384;

  bf16x8 qf[4];                          // B-frag: Q[q0+lo][c*16 + hi*8 + e]
#pragma unroll
  for (int c = 0; c < 4; ++c)
    qf[c] = *(const bf16x8*)(Qb + (size_t)(q0 + lo) * DK + c * 16 + hi * 8);

  // staging: 512 chunks/operand/group; group-thread tg stages chunks {tg, tg+256}
  const int tg = tid & 255;
  const int srow = tg >> 3;                               // 0..31 (and +32)
  const int ssrc = ((tg & 7) * 16) ^ ((srow & 7) << 4);   // pre-swizzled source

  f32x16 acc0 = {}, acc1 = {};           // O[q'][d], d = lo (+0 / +32)
  float mrun = -INFINITY, lrun = 0.f;
  int cur = 0;

  // prologue: stage tile 0 into buffer 0
  gld_lds16(Kb + (size_t)srow * 128 + ssrc,          Kg + tg * 16);
  gld_lds16(Kb + (size_t)(srow + 32) * 128 + ssrc,   Kg + 4096 + tg * 16);
  gld_lds16(Vb + (size_t)srow * 4096 + ssrc,         Vg + tg * 16);
  gld_lds16(Vb + (size_t)(srow + 32) * 4096 + ssrc,  Vg + 4096 + tg * 16);
  __syncthreads();

  for (int kt = 0; kt < 16; ++kt) {
    const char* Kc = Kg + cur * 8192;
    const char* Vc = Vg + cur * 8192;

    // async-stage next tile into the other buffer (lands before end barrier)
    if (kt + 1 < 16) {
      const char* Ksrc = Kb + (size_t)(kt + 1) * 8192;
      const char* Vsrc = Vb + (size_t)(kt + 1) * 128;
      char* Kn = Kg + (cur ^ 1) * 8192;
      char* Vn = Vg + (cur ^ 1) * 8192;
      gld_lds16(Ksrc + (size_t)srow * 128 + ssrc,         Kn + tg * 16);
      gld_lds16(Ksrc + (size_t)(srow + 32) * 128 + ssrc,  Kn + 4096 + tg * 16);
      gld_lds16(Vsrc + (size_t)srow * 4096 + ssrc,        Vn + tg * 16);
      gld_lds16(Vsrc + (size_t)(srow + 32) * 4096 + ssrc, Vn + 4096 + tg * 16);
    }

    // K fragments from swizzled LDS
    bf16x8 kf[2][4];
#pragma unroll
    for (int st = 0; st < 2; ++st)
#pragma unroll
      for (int c = 0; c < 4; ++c) {
        int row = st * 32 + lo;
        kf[st][c] = *(const bf16x8*)(Kc + row * 128 +
                                     (((2 * c + hi) * 16) ^ ((row & 7) << 4)));
      }

    f32x16 s0 = {}, s1 = {};
    __builtin_amdgcn_s_setprio(1);
#pragma unroll
    for (int c = 0; c < 4; ++c)
      s0 = __builtin_amdgcn_mfma_f32_32x32x16_bf16(kf[0][c], qf[c], s0, 0, 0, 0);
#pragma unroll
    for (int c = 0; c < 4; ++c)
      s1 = __builtin_amdgcn_mfma_f32_32x32x16_bf16(kf[1][c], qf[c], s1, 0, 0, 0);
    __builtin_amdgcn_s_setprio(0);

    // online softmax with defer-max (T13, THR=8 in exp2 domain)
    float pmax = -INFINITY;
#pragma unroll
    for (int r = 0; r < 16; ++r) pmax = fmaxf(pmax, fmaxf(s0[r], s1[r]));
    pmax = xhalf_max(pmax);

    if (!__all(pmax - mrun <= 8.f)) {    // wave-uniform, rare after tile 0
      float mnew = fmaxf(mrun, pmax);
      float corr = exp2f(mrun - mnew);
      lrun *= corr;
#pragma unroll
      for (int r = 0; r < 16; ++r) {
        int row = (r & 3) + 8 * (r >> 2) + 4 * hi;
        float cr = __shfl(corr, row);    // corr for O-row q' lives at lane q'
        acc0[r] *= cr;
        acc1[r] *= cr;
      }
      mrun = mnew;
    }

    float p[32];
    float psum = 0.f;
#pragma unroll
    for (int r = 0; r < 16; ++r) {
      p[r]      = exp2f(s0[r] - mrun);
      p[16 + r] = exp2f(s1[r] - mrun);
      psum += p[r] + p[16 + r];
    }
    lrun += xhalf_sum(psum);

    // P (C-layout) -> PV A-frags via pack + permlane32_swap (T12)
    bf16x8 pa[4];
#pragma unroll
    for (int g = 0; g < 4; ++g) {        // g = k-16-chunk within KV-64 tile
      unsigned c0 = pk2bf(p[g * 8 + 0], p[g * 8 + 1]);
      unsigned c1 = pk2bf(p[g * 8 + 2], p[g * 8 + 3]);
      unsigned c2 = pk2bf(p[g * 8 + 4], p[g * 8 + 5]);
      unsigned c3 = pk2bf(p[g * 8 + 6], p[g * 8 + 7]);
      uintx2 r02 = __builtin_amdgcn_permlane32_swap(c0, c2, false, false);
      uintx2 r13 = __builtin_amdgcn_permlane32_swap(c1, c3, false, false);
      uint4 w;
      w.x = r02[0];
      w.y = r13[0];
      w.z = r02[1];
      w.w = r13[1];
      pa[g] = __builtin_bit_cast(bf16x8, w);
    }

    // V^T fragments from swizzled LDS
    bf16x8 vf[2][4];
#pragma unroll
    for (int dt = 0; dt < 2; ++dt)
#pragma unroll
      for (int ks = 0; ks < 4; ++ks) {
        int row = dt * 32 + lo;
        vf[dt][ks] = *(const bf16x8*)(Vc + row * 128 +
                                      (((2 * ks + hi) * 16) ^ ((row & 7) << 4)));
      }

    __builtin_amdgcn_s_setprio(1);
#pragma unroll
    for (int ks = 0; ks < 4; ++ks) {
      acc0 = __builtin_amdgcn_mfma_f32_32x32x16_bf16(pa[ks], vf[0][ks], acc0, 0, 0, 0);
      acc1 = __builtin_amdgcn_mfma_f32_32x32x16_bf16(pa[ks], vf[1][ks], acc1, 0, 0, 0);
    }
    __builtin_amdgcn_s_setprio(0);

    __syncthreads();                     // drains stage loads; fences dbuf swap
    cur ^= 1;
  }

  // ---- in-block merge of the two KV halves (through LDS, once) ----
  float* Ml = (float*)lds;               // [grp][m|l][128 q-rows] = 2 KB
  float* U1 = (float*)(lds + 4096);      // group-1 U: [4 wq][64 lane][32] = 32 KB
  if (hi == 0) {
    Ml[grp * 256 + wq * 32 + lo]       = mrun;
    Ml[grp * 256 + 128 + wq * 32 + lo] = lrun;
  }
  if (grp == 1) {
    float* dst = U1 + (size_t)(wq * 64 + lane) * 32;
#pragma unroll
    for (int r = 0; r < 16; ++r) { dst[r] = acc0[r]; dst[16 + r] = acc1[r]; }
  }
  __syncthreads();
  if (grp == 0) {
    const float* src = U1 + (size_t)(wq * 64 + lane) * 32;
    int b = bh >> 4, h = bh & 15;
#pragma unroll
    for (int r = 0; r < 16; ++r) {
      int row = (r & 3) + 8 * (r >> 2) + 4 * hi;
      int gr = wq * 32 + row;
      float mA = Ml[gr],       lA = Ml[128 + gr];
      float mB = Ml[256 + gr], lB = Ml[384 + gr];
      float ms = fmaxf(mA, mB);
      float wA = exp2f(mA - ms), wB = exp2f(mB - ms);
      float linv = 1.f / (lA * wA + lB * wB);
      float o0 = (acc0[r] * wA + src[r] * wB) * linv;
      float o1 = (acc1[r] * wA + src[16 + r] * wB) * linv;
      int srw = q0 + row;
      size_t base = ((size_t)(b * SEQ + srw)) * D_MODEL + h * 64 + lo;
      ctx[base]      = (bf16)o0;
      ctx[base + 32] = (bf16)o1;
    }
  }
}

// ---------------- launch -----------------------------------------------------
extern "C" void kernel_launch(void* const* d_in, const int* in_sizes, int n_in,
                              void* d_out, int out_size, void* d_ws, size_t ws_size,
                              hipStream_t stream) {
  const float* query = (const float*)d_in[0];
  const float* key_  = (const float*)d_in[1];
  const float* value = (const float*)d_in[2];
  const float* w_q = (const float*)d_in[3];
  const float* b_q = (const float*)d_in[4];
  const float* w_k = (const float*)d_in[5];
  const float* b_k = (const float*)d_in[6];
  const float* w_v = (const float*)d_in[7];
  const float* b_v = (const float*)d_in[8];
  const float* w_o = (const float*)d_in[9];
  const float* b_o = (const float*)d_in[10];

  char* ws = (char*)d_ws;
  const size_t MB = 1024 * 1024;
  bf16* bQ  = (bf16*)(ws + 0 * MB);
  bf16* bK  = (bf16*)(ws + 8 * MB);
  bf16* bV  = (bf16*)(ws + 16 * MB);
  bf16* bWq = (bf16*)(ws + 24 * MB);
  bf16* bWk = (bf16*)(ws + 26 * MB);
  bf16* bWv = (bf16*)(ws + 28 * MB);
  bf16* bWo = (bf16*)(ws + 30 * MB);
  bf16* Qh  = (bf16*)(ws + 32 * MB);   // [b][h][s][d]  (pre-scaled by log2e/8)
  bf16* Kh  = (bf16*)(ws + 40 * MB);   // [b][h][s][d]
  bf16* Vth = (bf16*)(ws + 48 * MB);   // [b][h][d][s]
  bf16* ctx = (bf16*)(ws + 56 * MB);   // [b*s][d_model]

  ConvArgs ca;
  ca.src[0] = query; ca.src[1] = key_; ca.src[2] = value;
  ca.src[3] = w_q;   ca.src[4] = w_k;  ca.src[5] = w_v; ca.src[6] = w_o;
  ca.dst[0] = bQ;  ca.dst[1] = bK;  ca.dst[2] = bV;
  ca.dst[3] = bWq; ca.dst[4] = bWk; ca.dst[5] = bWv; ca.dst[6] = bWo;
  convert_f32_bf16<<<16384, 256, 0, stream>>>(ca);

  QkvArgs qa;
  qa.A[0] = bQ;  qa.B[0] = bWq; qa.bias[0] = b_q; qa.out[0] = Qh;
  qa.A[1] = bK;  qa.B[1] = bWk; qa.bias[1] = b_k; qa.out[1] = Kh;
  qa.A[2] = bWv; qa.B[2] = bV;  qa.bias[2] = b_v; qa.out[2] = Vth;
  gemm_qkv<<<dim3(32, 8, 3), 256, 0, stream>>>(qa);

  flash_attn<<<dim3(32, 16), 512, 0, stream>>>(Qh, Kh, Vth, ctx);

  gemm_o<<<dim3(64, 8), 256, 0, stream>>>(ctx, bWo, b_o, (float*)d_out);
}